// Round 21
// baseline (191.079 us; speedup 1.0000x reference)
//
#include <hip/hip_runtime.h>

typedef __attribute__((ext_vector_type(8))) short short8;
typedef __attribute__((ext_vector_type(4))) float f32x4;
typedef __attribute__((ext_vector_type(4))) int i32x4;

#define NSEQ 4096
#define MSEQ 1024
#define HID  512
#define CTXD 768

static __device__ __forceinline__ unsigned short f2bf(float f) {
  union { float f; unsigned u; } v; v.f = f;
  return (unsigned short)((v.u + 0x7fffu + ((v.u >> 16) & 1u)) >> 16);
}
static __device__ __forceinline__ float bf2f(unsigned short u) {
  union { unsigned u; float f; } v; v.u = ((unsigned)u) << 16;
  return v.f;
}

static __device__ __forceinline__ void gld16(const void* g, void* l) {
  __builtin_amdgcn_global_load_lds((const __attribute__((address_space(1))) void*)g,
                                   (__attribute__((address_space(3))) void*)l, 16, 0, 0);
}

// ------------- merged weight transpose: 4 weights in one launch ---------------
// z=0: Wq(512x512) z=1: Wk(768x512) z=2: Wv(768x512) z=3: Wo(512x512)
__global__ void k_transpose4(const float* __restrict__ W0, const float* __restrict__ W1,
                             const float* __restrict__ W2, const float* __restrict__ W3,
                             unsigned short* __restrict__ T0, unsigned short* __restrict__ T1,
                             unsigned short* __restrict__ T2, unsigned short* __restrict__ T3) {
  __shared__ float tile[32][33];
  const int zz = blockIdx.z;
  const float* W; unsigned short* T; int K;
  if (zz == 0)      { W = W0; T = T0; K = 512; }
  else if (zz == 1) { W = W1; T = T1; K = 768; }
  else if (zz == 2) { W = W2; T = T2; K = 768; }
  else              { W = W3; T = T3; K = 512; }
  int k0 = blockIdx.x * 32, n0 = blockIdx.y * 32;
  if (k0 >= K) return;
  const int N = 512;
  int tx = threadIdx.x, ty = threadIdx.y;
#pragma unroll
  for (int i = 0; i < 32; i += 8)
    tile[ty + i][tx] = W[(size_t)(k0 + ty + i) * N + n0 + tx];
  __syncthreads();
#pragma unroll
  for (int i = 0; i < 32; i += 8)
    T[(size_t)(n0 + ty + i) * K + k0 + tx] = f2bf(tile[tx][ty + i]);
}

// ---------------- GEMM 128x128 (R2-proven): C = A[M][K] * BT[N][K]^T ------------
// ldb = row stride (elements) of BT. ZMODE 0: grid (mx,ny,nz).
// ZMODE 2: flat grid, z=bid&7, r=bid>>3, m=r>>3, n=r&7.
template<int BIAS_MODE, bool RES, bool OUT_BF16, int ZMODE>
__global__ __launch_bounds__(256, 2) void k_gemm(
    const unsigned short* __restrict__ A, const unsigned short* __restrict__ B,
    const float* __restrict__ bias, const float* __restrict__ resv,
    void* __restrict__ Cv, int M, int N, int K,
    long sA, long sB, long sC, long sR, long ldb) {
  __shared__ __align__(16) char lds[65536];
  const int t = threadIdx.x, lane = t & 63, wid = t >> 6;
  const int wr = wid >> 1, wc = wid & 1;
  int m0, n0, z;
  if (ZMODE == 2) {
    int bid = blockIdx.x; z = bid & 7; int r = bid >> 3;
    m0 = (r >> 3) * 128; n0 = (r & 7) * 128;
  } else {
    m0 = blockIdx.x * 128; n0 = blockIdx.y * 128; z = blockIdx.z;
  }
  const unsigned short* Ab = A + (size_t)z * sA;
  const unsigned short* Bb = B + (size_t)z * sB;

  const f32x4 fz = {0.f, 0.f, 0.f, 0.f};
  f32x4 acc[4][4];
#pragma unroll
  for (int i = 0; i < 4; i++)
#pragma unroll
    for (int j = 0; j < 4; j++) acc[i][j] = fz;

  const int srow = t >> 3;      // 0..31
  const int schunk = t & 7;

  auto stage = [&](int kk, int buf) {
    const char* a8 = (const char*)Ab;
    const char* b8 = (const char*)Bb;
#pragma unroll
    for (int i = 0; i < 4; i++) {
      int row = i * 32 + srow;
      gld16(a8 + ((size_t)(m0 + row) * K + kk) * 2 + ((schunk ^ (row & 7)) << 4),
            lds + buf * 32768 + i * 4096 + wid * 1024);
    }
#pragma unroll
    for (int i = 0; i < 4; i++) {
      int row = i * 32 + srow;
      gld16(b8 + ((size_t)(n0 + row) * ldb + kk) * 2 + ((schunk ^ (row & 7)) << 4),
            lds + buf * 32768 + 16384 + i * 4096 + wid * 1024);
    }
  };

  stage(0, 0);
  int buf = 0;
  for (int kk = 0; kk < K; kk += 64) {
    if (kk + 64 < K) {
      stage(kk + 64, buf ^ 1);
      asm volatile("s_waitcnt vmcnt(8)" ::: "memory");
    } else {
      asm volatile("s_waitcnt vmcnt(0)" ::: "memory");
    }
    __builtin_amdgcn_s_barrier();
    const char* As = lds + buf * 32768;
    const char* Bs = As + 16384;
#pragma unroll
    for (int ks = 0; ks < 2; ks++) {
      short8 af[4], bfr[4];
#pragma unroll
      for (int i = 0; i < 4; i++) {
        int r = wr * 64 + i * 16 + (lane & 15);
        af[i] = *(const short8*)(As + r * 128 +
                 (((unsigned)(ks * 64 + (lane >> 4) * 16)) ^ ((unsigned)(r & 7) << 4)));
      }
#pragma unroll
      for (int i = 0; i < 4; i++) {
        int r = wc * 64 + i * 16 + (lane & 15);
        bfr[i] = *(const short8*)(Bs + r * 128 +
                 (((unsigned)(ks * 64 + (lane >> 4) * 16)) ^ ((unsigned)(r & 7) << 4)));
      }
#pragma unroll
      for (int i = 0; i < 4; i++)
#pragma unroll
        for (int j = 0; j < 4; j++)
          acc[i][j] = __builtin_amdgcn_mfma_f32_16x16x32_bf16(af[i], bfr[j], acc[i][j], 0, 0, 0);
    }
    asm volatile("s_waitcnt lgkmcnt(0)" ::: "memory");
    __builtin_amdgcn_s_barrier();
    buf ^= 1;
  }

  const float* res = RES ? (resv + (size_t)z * sR) : nullptr;
  char* Cb = (char*)Cv + (size_t)z * sC * (OUT_BF16 ? 2 : 4);
#pragma unroll
  for (int i = 0; i < 4; i++) {
#pragma unroll
    for (int jj = 0; jj < 4; jj++) {
      int row = m0 + wr * 64 + i * 16 + (lane >> 4) * 4 + jj;
#pragma unroll
      for (int j = 0; j < 4; j++) {
        int col = n0 + wc * 64 + j * 16 + (lane & 15);
        float v = acc[i][j][jj];
        if (BIAS_MODE == 1) v += bias[col];
        if (BIAS_MODE == 2) v += bias[row];
        if (RES) v += res[(size_t)row * N + col];
        if (OUT_BF16) ((unsigned short*)Cb)[(size_t)row * N + col] = f2bf(v);
        else          ((float*)Cb)[(size_t)row * N + col] = v;
      }
    }
  }
}

// ---------------- GEMM 256x256, BK=32, 8 waves (2x4), 3-buffer ring -------------
// R14 configuration: single-phase K-loop, ONE barrier per tile, compiler-
// scheduled lgkmcnt; scalar epilogues. EPI==2 precomputes 1/rowsum into LDS.
// AF32 path: A read as f32, converted in registers during staging.
// ldb = row stride (elements) of BT.
// ZMODE 0: grid (mx,ny,nz). ZMODE 1: flat, z=bid&7, r=bid>>3, m=r>>1, n=r&1.
// ZMODE 3: flat, z=bid&7, r=bid>>3, m=r>>2, n=r&3.
// EPI 0: bias/res. EPI 1: bf16(exp(acc*scale)) + deterministic partial row-sums.
// EPI 2: multiply by invb[row] before bias/res/store (softmax-normalized GEMM).
template<int BIAS_MODE, bool RES, bool OUT_BF16, int ZMODE, int EPI, bool AF32>
__global__ __launch_bounds__(512, 1) void k_gemm3(
    const unsigned short* __restrict__ A, const unsigned short* __restrict__ B,
    const float* __restrict__ bias, const float* __restrict__ resv,
    void* __restrict__ Cv, int M, int N, int K,
    long sA, long sB, long sC, long sR, long ldb,
    const float* __restrict__ ps, float* __restrict__ psout) {
  __shared__ __align__(16) char lds[99328];   // 3 x 32768 ring + 1024 invb
  const int t = threadIdx.x, lane = t & 63, wid = t >> 6;
  const int wr = wid >> 2, wc = wid & 3;
  const int l15 = lane & 15, g = lane >> 4;
  int m0, n0, z;
  if (ZMODE == 1) {
    int bid = blockIdx.x; z = bid & 7; int r = bid >> 3;
    m0 = (r >> 1) * 256; n0 = (r & 1) * 256;
  } else if (ZMODE == 3) {
    int bid = blockIdx.x; z = bid & 7; int r = bid >> 3;
    m0 = (r >> 2) * 256; n0 = (r & 3) * 256;
  } else {
    m0 = blockIdx.x * 256; n0 = blockIdx.y * 256; z = blockIdx.z;
  }
  const unsigned short* Ab = A + (size_t)z * sA;
  const float* Af = (const float*)A + (size_t)z * sA;
  const unsigned short* Bb = B + (size_t)z * sB;

  float* invb = (float*)(lds + 98304);   // [256] (EPI==2 only)
  if (EPI == 2) {
    if (t < 256) {
      size_t rr = (size_t)z * 4096 + (m0 + t);
      invb[t] = 1.0f / (ps[rr] + ps[32768 + rr] + ps[65536 + rr] + ps[98304 + rr]);
    }
    __syncthreads();
  }

  const f32x4 fz = {0.f, 0.f, 0.f, 0.f};
  f32x4 acc[8][4];
#pragma unroll
  for (int i = 0; i < 8; i++)
#pragma unroll
    for (int j = 0; j < 4; j++) acc[i][j] = fz;

  // per-lane inverse map for staging: LDS byte p -> logical (row, colbyte)
  int rS[2], cS[2];
#pragma unroll
  for (int u = 0; u < 2; u++) {
    int p = u * 8192 + wid * 1024 + lane * 16;
    int L = p >> 7;
    int q = (p & 127) ^ ((L & 7) << 4);
    rS[u] = 2 * L + (q >> 6);
    cS[u] = q & 63;
  }

  auto stageA = [&](int kk, int buf, int u) {
    gld16((const char*)Ab + ((size_t)(m0 + rS[u]) * K + kk) * 2 + cS[u],
          lds + buf * 32768 + u * 8192 + wid * 1024);
  };
  auto stageB = [&](int kk, int buf, int u) {
    gld16((const char*)Bb + ((size_t)(n0 + rS[u]) * ldb + kk) * 2 + cS[u],
          lds + buf * 32768 + 16384 + u * 8192 + wid * 1024);
  };

  // AF32 reg-staging: raw f32 A data for one tile (2 sub-steps x 8 floats)
  f32x4 araw[2][2];
  auto loadAraw = [&](int kk) {
#pragma unroll
    for (int u = 0; u < 2; u++) {
      const float* src = Af + (size_t)(m0 + rS[u]) * K + kk + (cS[u] >> 1);
      araw[u][0] = *(const f32x4*)(src);
      araw[u][1] = *(const f32x4*)(src + 4);
    }
  };
  auto writeA = [&](int buf) {
#pragma unroll
    for (int u = 0; u < 2; u++) {
      unsigned short tmp[8] __attribute__((aligned(16)));
#pragma unroll
      for (int e = 0; e < 4; e++) tmp[e] = f2bf(araw[u][0][e]);
#pragma unroll
      for (int e = 0; e < 4; e++) tmp[4 + e] = f2bf(araw[u][1][e]);
      *(i32x4*)(lds + buf * 32768 + u * 8192 + wid * 1024 + lane * 16) = *(const i32x4*)tmp;
    }
  };

  auto ldso = [&](int r, int gg) -> unsigned {
    unsigned L = (unsigned)(r >> 1);
    return L * 128 + ((((unsigned)(r & 1)) * 64 + (unsigned)gg * 16) ^ ((L & 7) << 4));
  };

  const int NT = K >> 5;
  if (AF32) {
    loadAraw(0);
#pragma unroll
    for (int u = 0; u < 2; u++) stageB(0, 0, u);
    writeA(0);
    loadAraw(32);
#pragma unroll
    for (int u = 0; u < 2; u++) stageB(32, 1, u);
    writeA(1);
  } else {
#pragma unroll
    for (int u = 0; u < 2; u++) { stageA(0, 0, u); }
#pragma unroll
    for (int u = 0; u < 2; u++) { stageB(0, 0, u); }
#pragma unroll
    for (int u = 0; u < 2; u++) { stageA(32, 1, u); }
#pragma unroll
    for (int u = 0; u < 2; u++) { stageB(32, 1, u); }
  }

  for (int tt = 0; tt < NT; tt++) {
    if (AF32) {
      asm volatile("s_waitcnt vmcnt(0)" ::: "memory");
    } else if (tt + 1 < NT) {
      asm volatile("s_waitcnt vmcnt(4)" ::: "memory");
    } else {
      asm volatile("s_waitcnt vmcnt(0)" ::: "memory");
    }
    __builtin_amdgcn_s_barrier();
    asm volatile("" ::: "memory");   // fence: no reads hoist above barrier
    const char* As = lds + (tt % 3) * 32768;
    const char* Bs = As + 16384;
    const int kk2 = (tt + 2) << 5;
    const bool st = kk2 < K;
    const int bn = (tt + 2) % 3;

    if (AF32 && st) loadAraw(kk2);   // issue early; consumed after MFMAs

    short8 bfr[4], af[8];
#pragma unroll
    for (int fj = 0; fj < 4; fj++) {
      int r = wc * 64 + fj * 16 + l15;
      bfr[fj] = *(const short8*)(Bs + ldso(r, g));
    }
#pragma unroll
    for (int fi = 0; fi < 8; fi++) {
      int r = wr * 128 + fi * 16 + l15;
      af[fi] = *(const short8*)(As + ldso(r, g));
    }
    if (!AF32 && st) { stageA(kk2, bn, 0); stageA(kk2, bn, 1); stageB(kk2, bn, 0); stageB(kk2, bn, 1); }
    __builtin_amdgcn_s_setprio(1);
#pragma unroll
    for (int fi = 0; fi < 8; fi++)
#pragma unroll
      for (int fj = 0; fj < 4; fj++)
        acc[fi][fj] =
            __builtin_amdgcn_mfma_f32_16x16x32_bf16(af[fi], bfr[fj], acc[fi][fj], 0, 0, 0);
    __builtin_amdgcn_s_setprio(0);
    if (AF32 && st) { writeA(bn); stageB(kk2, bn, 0); stageB(kk2, bn, 1); }
    asm volatile("" ::: "memory");   // fence: no reads sink below this point
  }
  asm volatile("s_waitcnt lgkmcnt(0)" ::: "memory");
  __builtin_amdgcn_s_barrier();   // ring dead; epilogue may reuse LDS (EPI=1 redb)
  asm volatile("" ::: "memory");

  char* Cb = (char*)Cv + (size_t)z * sC * (OUT_BF16 ? 2 : 4);

  if (EPI == 1) {
    // exp epilogue: store bf16(exp(acc*scale)); deterministic partial row-sums.
    const float scale = 0.044194173824159216f;  // 512^-0.5
    float* redb = (float*)lds;                  // [4][256] (ring is dead)
#pragma unroll
    for (int i = 0; i < 8; i++) {
#pragma unroll
      for (int jj = 0; jj < 4; jj++) {
        int rl = wr * 128 + i * 16 + g * 4 + jj;   // row within tile
        int row = m0 + rl;
        float e4 = 0.f;
#pragma unroll
        for (int j = 0; j < 4; j++) {
          int col = n0 + wc * 64 + j * 16 + l15;
          float e = __expf(acc[i][j][jj] * scale);
          unsigned short h = f2bf(e);
          ((unsigned short*)Cb)[(size_t)row * N + col] = h;
          e4 += bf2f(h);
        }
#pragma unroll
        for (int d = 1; d < 16; d <<= 1) e4 += __shfl_xor(e4, d, 64);
        if (l15 == 0) redb[wc * 256 + rl] = e4;
      }
    }
    __syncthreads();
    if (t < 256) {
      float s4 = redb[t] + redb[256 + t] + redb[512 + t] + redb[768 + t];
      psout[(size_t)(n0 >> 8) * 32768 + (size_t)z * 4096 + (m0 + t)] = s4;
    }
    return;
  }

  const float* res = RES ? (resv + (size_t)z * sR) : nullptr;
#pragma unroll
  for (int i = 0; i < 8; i++) {
#pragma unroll
    for (int jj = 0; jj < 4; jj++) {
      int rl = wr * 128 + i * 16 + g * 4 + jj;
      int row = m0 + rl;
      float inv = 1.0f;
      if (EPI == 2) inv = invb[rl];
#pragma unroll
      for (int j = 0; j < 4; j++) {
        int col = n0 + wc * 64 + j * 16 + l15;
        float v = acc[i][j][jj];
        if (EPI == 2) v *= inv;
        if (BIAS_MODE == 1) v += bias[col];
        if (BIAS_MODE == 2) v += bias[row];
        if (RES) v += res[(size_t)row * N + col];
        if (OUT_BF16) ((unsigned short*)Cb)[(size_t)row * N + col] = f2bf(v);
        else          ((float*)Cb)[(size_t)row * N + col] = v;
      }
    }
  }
}

// ---------------- launch ----------------
extern "C" void kernel_launch(void* const* d_in, const int* in_sizes, int n_in,
                              void* d_out, int out_size, void* d_ws, size_t ws_size,
                              hipStream_t stream) {
  (void)in_sizes; (void)n_in; (void)out_size; (void)ws_size;
  const float* x   = (const float*)d_in[0];
  const float* ctx = (const float*)d_in[1];
  const float* Wq  = (const float*)d_in[2];
  const float* bq  = (const float*)d_in[3];
  const float* Wk  = (const float*)d_in[4];
  const float* bk  = (const float*)d_in[5];
  const float* Wv  = (const float*)d_in[6];
  const float* bv  = (const float*)d_in[7];
  const float* Wo  = (const float*)d_in[8];
  const float* bo  = (const float*)d_in[9];
  float* out = (float*)d_out;

  char* ws = (char*)d_ws;
  unsigned short* qb   = (unsigned short*)(ws);              // 33,554,432
  unsigned short* kv   = (unsigned short*)(ws + 33554432);   // 16,777,216 [8192][1024]
  unsigned short* UT   = (unsigned short*)(ws + 50331648);   //  8,388,608 (U^T)
  unsigned short* WqT  = (unsigned short*)(ws + 58720256);   //    524,288
  unsigned short* WkT  = (unsigned short*)(ws + 59244544);   //    786,432  \ adjacent =
  unsigned short* WvT  = (unsigned short*)(ws + 60030976);   //    786,432  / WkvT [1024][768]
  unsigned short* WoT  = (unsigned short*)(ws + 60817408);   //    524,288 -> 61,341,696
  float* bkv           = (float*)(ws + 61341696);            //      4,096 -> 61,345,792
  unsigned short* Sbuf = (unsigned short*)(ws + 61345792);   // 67,108,864 -> 128,454,656
  float* psums         = (float*)(ws + 128454656);           //    524,288 -> 128,978,944

  // bkv = [bk ; bv]
  hipMemcpyAsync(bkv, bk, 512 * sizeof(float), hipMemcpyDeviceToDevice, stream);
  hipMemcpyAsync(bkv + 512, bv, 512 * sizeof(float), hipMemcpyDeviceToDevice, stream);

  // all 4 weight transposes in one launch
  k_transpose4<<<dim3(24, 16, 4), dim3(32, 8), 0, stream>>>(
      Wq, Wk, Wv, Wo, WqT, WkT, WvT, WoT);

  // q = x @ Wq + bq -> bf16 [32768][512]   (x consumed as f32: cast fused)
  k_gemm3<1, false, true, 0, 0, true><<<dim3(128, 2, 1), 512, 0, stream>>>(
      (const unsigned short*)x, WqT, bq, nullptr, qb, 32768, 512, 512,
      0, 0, 0, 0, 512, nullptr, nullptr);
  // kv = ctx @ [Wk|Wv] + [bk|bv] -> bf16 [8192][1024]  (ctx cast fused, k+V merged)
  k_gemm3<1, false, true, 0, 0, true><<<dim3(32, 4, 1), 512, 0, stream>>>(
      (const unsigned short*)ctx, WkT, bkv, nullptr, kv, 8192, 1024, 768,
      0, 0, 0, 0, 768, nullptr, nullptr);
  // UT[b] = WoT @ V[b]^T -> bf16 [8][512][1024]  (V = kv cols 512.., ldb=1024)
  k_gemm<0, false, true, 2><<<dim3(256), 256, 0, stream>>>(
      WoT, kv + 512, nullptr, nullptr, UT, 512, 1024, 512,
      0, (long)1024 * 1024, (long)512 * 1024, 0, 1024);
  // Pexp[b] = exp(q[b] k[b]^T * scale) -> bf16, + partial row-sums
  // (k = kv cols 0..511, ldb=1024)
  k_gemm3<0, false, true, 3, 1, false><<<dim3(512), 512, 0, stream>>>(
      qb, kv, nullptr, nullptr, Sbuf, 4096, 1024, 512,
      (long)4096 * 512, (long)1024 * 1024, (long)4096 * 1024, 0, 1024,
      nullptr, psums);
  // out[b] = (Pexp[b] @ UT[b]^T) / rowsum + bo + x[b] -> f32
  k_gemm3<1, true, false, 1, 2, false><<<dim3(256), 512, 0, stream>>>(
      Sbuf, UT, bo, x, out, 4096, 512, 1024,
      (long)4096 * 1024, (long)512 * 1024, (long)4096 * 512, (long)4096 * 512, 1024,
      psums, nullptr);
}

// Round 22
// 180.913 us; speedup vs baseline: 1.0562x; 1.0562x over previous
//
#include <hip/hip_runtime.h>

typedef __attribute__((ext_vector_type(8))) short short8;
typedef __attribute__((ext_vector_type(4))) float f32x4;
typedef __attribute__((ext_vector_type(4))) int i32x4;

#define NSEQ 4096
#define MSEQ 1024
#define HID  512
#define CTXD 768

static __device__ __forceinline__ unsigned short f2bf(float f) {
  union { float f; unsigned u; } v; v.f = f;
  return (unsigned short)((v.u + 0x7fffu + ((v.u >> 16) & 1u)) >> 16);
}
static __device__ __forceinline__ float bf2f(unsigned short u) {
  union { unsigned u; float f; } v; v.u = ((unsigned)u) << 16;
  return v.f;
}

static __device__ __forceinline__ void gld16(const void* g, void* l) {
  __builtin_amdgcn_global_load_lds((const __attribute__((address_space(1))) void*)g,
                                   (__attribute__((address_space(3))) void*)l, 16, 0, 0);
}

// ------------- merged weight transpose: 4 weights in one launch ---------------
// z=0: Wq(512x512) z=1: Wk(768x512) z=2: Wv(768x512) z=3: Wo(512x512)
__global__ void k_transpose4(const float* __restrict__ W0, const float* __restrict__ W1,
                             const float* __restrict__ W2, const float* __restrict__ W3,
                             unsigned short* __restrict__ T0, unsigned short* __restrict__ T1,
                             unsigned short* __restrict__ T2, unsigned short* __restrict__ T3) {
  __shared__ float tile[32][33];
  const int zz = blockIdx.z;
  const float* W; unsigned short* T; int K;
  if (zz == 0)      { W = W0; T = T0; K = 512; }
  else if (zz == 1) { W = W1; T = T1; K = 768; }
  else if (zz == 2) { W = W2; T = T2; K = 768; }
  else              { W = W3; T = T3; K = 512; }
  int k0 = blockIdx.x * 32, n0 = blockIdx.y * 32;
  if (k0 >= K) return;
  const int N = 512;
  int tx = threadIdx.x, ty = threadIdx.y;
#pragma unroll
  for (int i = 0; i < 32; i += 8)
    tile[ty + i][tx] = W[(size_t)(k0 + ty + i) * N + n0 + tx];
  __syncthreads();
#pragma unroll
  for (int i = 0; i < 32; i += 8)
    T[(size_t)(n0 + ty + i) * K + k0 + tx] = f2bf(tile[tx][ty + i]);
}

// ---------------- f32 -> bf16 cast, vectorized ----------------
__global__ void k_cast(const float* __restrict__ in, unsigned short* __restrict__ out, int n8) {
  int i = blockIdx.x * blockDim.x + threadIdx.x;
  int stride = gridDim.x * blockDim.x;
  for (; i < n8; i += stride) {
    f32x4 v0 = *(const f32x4*)(in + (size_t)i * 8);
    f32x4 v1 = *(const f32x4*)(in + (size_t)i * 8 + 4);
    unsigned short tmp[8] __attribute__((aligned(16)));
    tmp[0] = f2bf(v0[0]); tmp[1] = f2bf(v0[1]); tmp[2] = f2bf(v0[2]); tmp[3] = f2bf(v0[3]);
    tmp[4] = f2bf(v1[0]); tmp[5] = f2bf(v1[1]); tmp[6] = f2bf(v1[2]); tmp[7] = f2bf(v1[3]);
    *(i32x4*)(out + (size_t)i * 8) = *(const i32x4*)tmp;
  }
}

// ---------------- GEMM 128x128 (R2-proven): C = A[M][K] * BT[N][K]^T ------------
// ZMODE 0: grid (mx,ny,nz). ZMODE 2: flat grid, z=bid&7, r=bid>>3, m=r>>3, n=r&7.
template<int BIAS_MODE, bool RES, bool OUT_BF16, int ZMODE>
__global__ __launch_bounds__(256, 2) void k_gemm(
    const unsigned short* __restrict__ A, const unsigned short* __restrict__ B,
    const float* __restrict__ bias, const float* __restrict__ resv,
    void* __restrict__ Cv, int M, int N, int K,
    long sA, long sB, long sC, long sR) {
  __shared__ __align__(16) char lds[65536];
  const int t = threadIdx.x, lane = t & 63, wid = t >> 6;
  const int wr = wid >> 1, wc = wid & 1;
  int m0, n0, z;
  if (ZMODE == 2) {
    int bid = blockIdx.x; z = bid & 7; int r = bid >> 3;
    m0 = (r >> 3) * 128; n0 = (r & 7) * 128;
  } else {
    m0 = blockIdx.x * 128; n0 = blockIdx.y * 128; z = blockIdx.z;
  }
  const unsigned short* Ab = A + (size_t)z * sA;
  const unsigned short* Bb = B + (size_t)z * sB;

  const f32x4 fz = {0.f, 0.f, 0.f, 0.f};
  f32x4 acc[4][4];
#pragma unroll
  for (int i = 0; i < 4; i++)
#pragma unroll
    for (int j = 0; j < 4; j++) acc[i][j] = fz;

  const int srow = t >> 3;      // 0..31
  const int schunk = t & 7;

  auto stage = [&](int kk, int buf) {
    const char* a8 = (const char*)Ab;
    const char* b8 = (const char*)Bb;
#pragma unroll
    for (int i = 0; i < 4; i++) {
      int row = i * 32 + srow;
      gld16(a8 + ((size_t)(m0 + row) * K + kk) * 2 + ((schunk ^ (row & 7)) << 4),
            lds + buf * 32768 + i * 4096 + wid * 1024);
    }
#pragma unroll
    for (int i = 0; i < 4; i++) {
      int row = i * 32 + srow;
      gld16(b8 + ((size_t)(n0 + row) * K + kk) * 2 + ((schunk ^ (row & 7)) << 4),
            lds + buf * 32768 + 16384 + i * 4096 + wid * 1024);
    }
  };

  stage(0, 0);
  int buf = 0;
  for (int kk = 0; kk < K; kk += 64) {
    if (kk + 64 < K) {
      stage(kk + 64, buf ^ 1);
      asm volatile("s_waitcnt vmcnt(8)" ::: "memory");
    } else {
      asm volatile("s_waitcnt vmcnt(0)" ::: "memory");
    }
    __builtin_amdgcn_s_barrier();
    const char* As = lds + buf * 32768;
    const char* Bs = As + 16384;
#pragma unroll
    for (int ks = 0; ks < 2; ks++) {
      short8 af[4], bfr[4];
#pragma unroll
      for (int i = 0; i < 4; i++) {
        int r = wr * 64 + i * 16 + (lane & 15);
        af[i] = *(const short8*)(As + r * 128 +
                 (((unsigned)(ks * 64 + (lane >> 4) * 16)) ^ ((unsigned)(r & 7) << 4)));
      }
#pragma unroll
      for (int i = 0; i < 4; i++) {
        int r = wc * 64 + i * 16 + (lane & 15);
        bfr[i] = *(const short8*)(Bs + r * 128 +
                 (((unsigned)(ks * 64 + (lane >> 4) * 16)) ^ ((unsigned)(r & 7) << 4)));
      }
#pragma unroll
      for (int i = 0; i < 4; i++)
#pragma unroll
        for (int j = 0; j < 4; j++)
          acc[i][j] = __builtin_amdgcn_mfma_f32_16x16x32_bf16(af[i], bfr[j], acc[i][j], 0, 0, 0);
    }
    asm volatile("s_waitcnt lgkmcnt(0)" ::: "memory");
    __builtin_amdgcn_s_barrier();
    buf ^= 1;
  }

  const float* res = RES ? (resv + (size_t)z * sR) : nullptr;
  char* Cb = (char*)Cv + (size_t)z * sC * (OUT_BF16 ? 2 : 4);
#pragma unroll
  for (int i = 0; i < 4; i++) {
#pragma unroll
    for (int jj = 0; jj < 4; jj++) {
      int row = m0 + wr * 64 + i * 16 + (lane >> 4) * 4 + jj;
#pragma unroll
      for (int j = 0; j < 4; j++) {
        int col = n0 + wc * 64 + j * 16 + (lane & 15);
        float v = acc[i][j][jj];
        if (BIAS_MODE == 1) v += bias[col];
        if (BIAS_MODE == 2) v += bias[row];
        if (RES) v += res[(size_t)row * N + col];
        if (OUT_BF16) ((unsigned short*)Cb)[(size_t)row * N + col] = f2bf(v);
        else          ((float*)Cb)[(size_t)row * N + col] = v;
      }
    }
  }
}

// ---------------- GEMM 256x256, BK=32, 8 waves (2x4), 3-buffer ring -------------
// R14 configuration: single-phase K-loop, ONE barrier per tile, compiler-
// scheduled lgkmcnt; scalar epilogues. EPI==2 precomputes 1/rowsum into LDS.
// AF32 path (q-GEMM): A read as f32, converted in registers during staging.
// ZMODE 0: grid (mx,ny,nz). ZMODE 1: flat, z=bid&7, r=bid>>3, m=r>>1, n=r&1.
// ZMODE 3: flat, z=bid&7, r=bid>>3, m=r>>2, n=r&3.
// EPI 0: bias/res. EPI 1: bf16(exp(acc*scale)) + deterministic partial row-sums.
// EPI 2: multiply by invb[row] before bias/res/store (softmax-normalized GEMM).
template<int BIAS_MODE, bool RES, bool OUT_BF16, int ZMODE, int EPI, bool AF32>
__global__ __launch_bounds__(512, 1) void k_gemm3(
    const unsigned short* __restrict__ A, const unsigned short* __restrict__ B,
    const float* __restrict__ bias, const float* __restrict__ resv,
    void* __restrict__ Cv, int M, int N, int K,
    long sA, long sB, long sC, long sR,
    const float* __restrict__ ps, float* __restrict__ psout) {
  __shared__ __align__(16) char lds[99328];   // 3 x 32768 ring + 1024 invb
  const int t = threadIdx.x, lane = t & 63, wid = t >> 6;
  const int wr = wid >> 2, wc = wid & 3;
  const int l15 = lane & 15, g = lane >> 4;
  int m0, n0, z;
  if (ZMODE == 1) {
    int bid = blockIdx.x; z = bid & 7; int r = bid >> 3;
    m0 = (r >> 1) * 256; n0 = (r & 1) * 256;
  } else if (ZMODE == 3) {
    int bid = blockIdx.x; z = bid & 7; int r = bid >> 3;
    m0 = (r >> 2) * 256; n0 = (r & 3) * 256;
  } else {
    m0 = blockIdx.x * 256; n0 = blockIdx.y * 256; z = blockIdx.z;
  }
  const unsigned short* Ab = A + (size_t)z * sA;
  const float* Af = (const float*)A + (size_t)z * sA;
  const unsigned short* Bb = B + (size_t)z * sB;

  float* invb = (float*)(lds + 98304);   // [256] (EPI==2 only)
  if (EPI == 2) {
    if (t < 256) {
      size_t rr = (size_t)z * 4096 + (m0 + t);
      invb[t] = 1.0f / (ps[rr] + ps[32768 + rr] + ps[65536 + rr] + ps[98304 + rr]);
    }
    __syncthreads();
  }

  const f32x4 fz = {0.f, 0.f, 0.f, 0.f};
  f32x4 acc[8][4];
#pragma unroll
  for (int i = 0; i < 8; i++)
#pragma unroll
    for (int j = 0; j < 4; j++) acc[i][j] = fz;

  // per-lane inverse map for staging: LDS byte p -> logical (row, colbyte)
  int rS[2], cS[2];
#pragma unroll
  for (int u = 0; u < 2; u++) {
    int p = u * 8192 + wid * 1024 + lane * 16;
    int L = p >> 7;
    int q = (p & 127) ^ ((L & 7) << 4);
    rS[u] = 2 * L + (q >> 6);
    cS[u] = q & 63;
  }

  auto stageA = [&](int kk, int buf, int u) {
    gld16((const char*)Ab + ((size_t)(m0 + rS[u]) * K + kk) * 2 + cS[u],
          lds + buf * 32768 + u * 8192 + wid * 1024);
  };
  auto stageB = [&](int kk, int buf, int u) {
    gld16((const char*)Bb + ((size_t)(n0 + rS[u]) * K + kk) * 2 + cS[u],
          lds + buf * 32768 + 16384 + u * 8192 + wid * 1024);
  };

  // AF32 reg-staging: raw f32 A data for one tile (2 sub-steps x 8 floats)
  f32x4 araw[2][2];
  auto loadAraw = [&](int kk) {
#pragma unroll
    for (int u = 0; u < 2; u++) {
      const float* src = Af + (size_t)(m0 + rS[u]) * K + kk + (cS[u] >> 1);
      araw[u][0] = *(const f32x4*)(src);
      araw[u][1] = *(const f32x4*)(src + 4);
    }
  };
  auto writeA = [&](int buf) {
#pragma unroll
    for (int u = 0; u < 2; u++) {
      unsigned short tmp[8] __attribute__((aligned(16)));
#pragma unroll
      for (int e = 0; e < 4; e++) tmp[e] = f2bf(araw[u][0][e]);
#pragma unroll
      for (int e = 0; e < 4; e++) tmp[4 + e] = f2bf(araw[u][1][e]);
      *(i32x4*)(lds + buf * 32768 + u * 8192 + wid * 1024 + lane * 16) = *(const i32x4*)tmp;
    }
  };

  auto ldso = [&](int r, int gg) -> unsigned {
    unsigned L = (unsigned)(r >> 1);
    return L * 128 + ((((unsigned)(r & 1)) * 64 + (unsigned)gg * 16) ^ ((L & 7) << 4));
  };

  const int NT = K >> 5;
  if (AF32) {
    loadAraw(0);
#pragma unroll
    for (int u = 0; u < 2; u++) stageB(0, 0, u);
    writeA(0);
    loadAraw(32);
#pragma unroll
    for (int u = 0; u < 2; u++) stageB(32, 1, u);
    writeA(1);
  } else {
#pragma unroll
    for (int u = 0; u < 2; u++) { stageA(0, 0, u); }
#pragma unroll
    for (int u = 0; u < 2; u++) { stageB(0, 0, u); }
#pragma unroll
    for (int u = 0; u < 2; u++) { stageA(32, 1, u); }
#pragma unroll
    for (int u = 0; u < 2; u++) { stageB(32, 1, u); }
  }

  for (int tt = 0; tt < NT; tt++) {
    if (AF32) {
      asm volatile("s_waitcnt vmcnt(0)" ::: "memory");
    } else if (tt + 1 < NT) {
      asm volatile("s_waitcnt vmcnt(4)" ::: "memory");
    } else {
      asm volatile("s_waitcnt vmcnt(0)" ::: "memory");
    }
    __builtin_amdgcn_s_barrier();
    asm volatile("" ::: "memory");   // fence: no reads hoist above barrier
    const char* As = lds + (tt % 3) * 32768;
    const char* Bs = As + 16384;
    const int kk2 = (tt + 2) << 5;
    const bool st = kk2 < K;
    const int bn = (tt + 2) % 3;

    if (AF32 && st) loadAraw(kk2);   // issue early; consumed after MFMAs

    short8 bfr[4], af[8];
#pragma unroll
    for (int fj = 0; fj < 4; fj++) {
      int r = wc * 64 + fj * 16 + l15;
      bfr[fj] = *(const short8*)(Bs + ldso(r, g));
    }
#pragma unroll
    for (int fi = 0; fi < 8; fi++) {
      int r = wr * 128 + fi * 16 + l15;
      af[fi] = *(const short8*)(As + ldso(r, g));
    }
    if (!AF32 && st) { stageA(kk2, bn, 0); stageA(kk2, bn, 1); stageB(kk2, bn, 0); stageB(kk2, bn, 1); }
    __builtin_amdgcn_s_setprio(1);
#pragma unroll
    for (int fi = 0; fi < 8; fi++)
#pragma unroll
      for (int fj = 0; fj < 4; fj++)
        acc[fi][fj] =
            __builtin_amdgcn_mfma_f32_16x16x32_bf16(af[fi], bfr[fj], acc[fi][fj], 0, 0, 0);
    __builtin_amdgcn_s_setprio(0);
    if (AF32 && st) { writeA(bn); stageB(kk2, bn, 0); stageB(kk2, bn, 1); }
    asm volatile("" ::: "memory");   // fence: no reads sink below this point
  }
  asm volatile("s_waitcnt lgkmcnt(0)" ::: "memory");
  __builtin_amdgcn_s_barrier();   // ring dead; epilogue may reuse LDS (EPI=1 redb)
  asm volatile("" ::: "memory");

  char* Cb = (char*)Cv + (size_t)z * sC * (OUT_BF16 ? 2 : 4);

  if (EPI == 1) {
    // exp epilogue: store bf16(exp(acc*scale)); deterministic partial row-sums.
    const float scale = 0.044194173824159216f;  // 512^-0.5
    float* redb = (float*)lds;                  // [4][256] (ring is dead)
#pragma unroll
    for (int i = 0; i < 8; i++) {
#pragma unroll
      for (int jj = 0; jj < 4; jj++) {
        int rl = wr * 128 + i * 16 + g * 4 + jj;   // row within tile
        int row = m0 + rl;
        float e4 = 0.f;
#pragma unroll
        for (int j = 0; j < 4; j++) {
          int col = n0 + wc * 64 + j * 16 + l15;
          float e = __expf(acc[i][j][jj] * scale);
          unsigned short h = f2bf(e);
          ((unsigned short*)Cb)[(size_t)row * N + col] = h;
          e4 += bf2f(h);
        }
#pragma unroll
        for (int d = 1; d < 16; d <<= 1) e4 += __shfl_xor(e4, d, 64);
        if (l15 == 0) redb[wc * 256 + rl] = e4;
      }
    }
    __syncthreads();
    if (t < 256) {
      float s4 = redb[t] + redb[256 + t] + redb[512 + t] + redb[768 + t];
      psout[(size_t)(n0 >> 8) * 32768 + (size_t)z * 4096 + (m0 + t)] = s4;
    }
    return;
  }

  const float* res = RES ? (resv + (size_t)z * sR) : nullptr;
#pragma unroll
  for (int i = 0; i < 8; i++) {
#pragma unroll
    for (int jj = 0; jj < 4; jj++) {
      int rl = wr * 128 + i * 16 + g * 4 + jj;
      int row = m0 + rl;
      float inv = 1.0f;
      if (EPI == 2) inv = invb[rl];
#pragma unroll
      for (int j = 0; j < 4; j++) {
        int col = n0 + wc * 64 + j * 16 + l15;
        float v = acc[i][j][jj];
        if (EPI == 2) v *= inv;
        if (BIAS_MODE == 1) v += bias[col];
        if (BIAS_MODE == 2) v += bias[row];
        if (RES) v += res[(size_t)row * N + col];
        if (OUT_BF16) ((unsigned short*)Cb)[(size_t)row * N + col] = f2bf(v);
        else          ((float*)Cb)[(size_t)row * N + col] = v;
      }
    }
  }
}

// ---------------- launch ----------------
extern "C" void kernel_launch(void* const* d_in, const int* in_sizes, int n_in,
                              void* d_out, int out_size, void* d_ws, size_t ws_size,
                              hipStream_t stream) {
  (void)in_sizes; (void)n_in; (void)out_size; (void)ws_size;
  const float* x   = (const float*)d_in[0];
  const float* ctx = (const float*)d_in[1];
  const float* Wq  = (const float*)d_in[2];
  const float* bq  = (const float*)d_in[3];
  const float* Wk  = (const float*)d_in[4];
  const float* bk  = (const float*)d_in[5];
  const float* Wv  = (const float*)d_in[6];
  const float* bv  = (const float*)d_in[7];
  const float* Wo  = (const float*)d_in[8];
  const float* bo  = (const float*)d_in[9];
  float* out = (float*)d_out;

  char* ws = (char*)d_ws;
  unsigned short* qb   = (unsigned short*)(ws);              // 33,554,432
  unsigned short* kbuf = (unsigned short*)(ws + 33554432);   //  8,388,608
  unsigned short* Vb   = (unsigned short*)(ws + 41943040);   //  8,388,608 (V row-major)
  unsigned short* UT   = (unsigned short*)(ws + 50331648);   //  8,388,608 (U^T = (V Wo)^T)
  unsigned short* WqT  = (unsigned short*)(ws + 58720256);   //    524,288
  unsigned short* WkT  = (unsigned short*)(ws + 59244544);   //    786,432
  unsigned short* WvT  = (unsigned short*)(ws + 60030976);   //    786,432
  unsigned short* WoT  = (unsigned short*)(ws + 60817408);   //    524,288 -> 61,341,696
  unsigned short* cb   = (unsigned short*)(ws + 61341696);   // 12,582,912 -> 73,924,608
  unsigned short* Sbuf = (unsigned short*)(ws + 73924608);   // 67,108,864 -> 141,033,472
  float* psums = (float*)(ws + 141033472);                   // 524,288

  // all 4 weight transposes in one launch
  k_transpose4<<<dim3(24, 16, 4), dim3(32, 8), 0, stream>>>(
      Wq, Wk, Wv, Wo, WqT, WkT, WvT, WoT);

  k_cast<<<dim3(2048), 256, 0, stream>>>(ctx, cb, 786432);

  // q = x @ Wq + bq -> bf16 [32768][512]   (x consumed as f32: cast fused)
  k_gemm3<1, false, true, 0, 0, true><<<dim3(128, 2, 1), 512, 0, stream>>>(
      (const unsigned short*)x, WqT, bq, nullptr, qb, 32768, 512, 512,
      0, 0, 0, 0, nullptr, nullptr);
  // k = ctx @ Wk + bk -> bf16 [8192][512]
  k_gemm<1, false, true, 0><<<dim3(64, 4, 1), 256, 0, stream>>>(
      cb, WkT, bk, nullptr, kbuf, 8192, 512, 768, 0, 0, 0, 0);
  // V = ctx @ Wv + bv -> bf16 [8192][512] row-major
  k_gemm<1, false, true, 0><<<dim3(64, 4, 1), 256, 0, stream>>>(
      cb, WvT, bv, nullptr, Vb, 8192, 512, 768, 0, 0, 0, 0);
  // UT[b] = (V[b] @ Wo)^T = WoT @ V[b]^T -> bf16 [8][512][1024]  (z->XCD affinity)
  k_gemm<0, false, true, 2><<<dim3(256), 256, 0, stream>>>(
      WoT, Vb, nullptr, nullptr, UT, 512, 1024, 512,
      0, (long)1024 * 512, (long)512 * 1024, 0);
  // Pexp[b] = exp(q[b] k[b]^T * scale) -> bf16, + partial row-sums (softmax fused)
  k_gemm3<0, false, true, 3, 1, false><<<dim3(512), 512, 0, stream>>>(
      qb, kbuf, nullptr, nullptr, Sbuf, 4096, 1024, 512,
      (long)4096 * 512, (long)1024 * 512, (long)4096 * 1024, 0, nullptr, psums);
  // out[b] = (Pexp[b] @ UT[b]^T) / rowsum + bo + x[b] -> f32 (PV and out-proj merged)
  k_gemm3<1, true, false, 1, 2, false><<<dim3(256), 512, 0, stream>>>(
      Sbuf, UT, bo, x, out, 4096, 512, 1024,
      (long)4096 * 1024, (long)512 * 1024, (long)4096 * 512, (long)4096 * 512,
      psums, nullptr);
}

// Round 23
// 178.189 us; speedup vs baseline: 1.0723x; 1.0153x over previous
//
#include <hip/hip_runtime.h>

typedef __attribute__((ext_vector_type(8))) short short8;
typedef __attribute__((ext_vector_type(4))) float f32x4;
typedef __attribute__((ext_vector_type(4))) int i32x4;

#define NSEQ 4096
#define MSEQ 1024
#define HID  512
#define CTXD 768

static __device__ __forceinline__ unsigned short f2bf(float f) {
  union { float f; unsigned u; } v; v.f = f;
  return (unsigned short)((v.u + 0x7fffu + ((v.u >> 16) & 1u)) >> 16);
}
static __device__ __forceinline__ float bf2f(unsigned short u) {
  union { unsigned u; float f; } v; v.u = ((unsigned)u) << 16;
  return v.f;
}

static __device__ __forceinline__ void gld16(const void* g, void* l) {
  __builtin_amdgcn_global_load_lds((const __attribute__((address_space(1))) void*)g,
                                   (__attribute__((address_space(3))) void*)l, 16, 0, 0);
}

// ------------- merged weight transpose: 4 weights in one launch ---------------
// z=0: Wq(512x512) z=1: Wk(768x512) z=2: Wv(768x512) z=3: Wo(512x512)
__global__ void k_transpose4(const float* __restrict__ W0, const float* __restrict__ W1,
                             const float* __restrict__ W2, const float* __restrict__ W3,
                             unsigned short* __restrict__ T0, unsigned short* __restrict__ T1,
                             unsigned short* __restrict__ T2, unsigned short* __restrict__ T3) {
  __shared__ float tile[32][33];
  const int zz = blockIdx.z;
  const float* W; unsigned short* T; int K;
  if (zz == 0)      { W = W0; T = T0; K = 512; }
  else if (zz == 1) { W = W1; T = T1; K = 768; }
  else if (zz == 2) { W = W2; T = T2; K = 768; }
  else              { W = W3; T = T3; K = 512; }
  int k0 = blockIdx.x * 32, n0 = blockIdx.y * 32;
  if (k0 >= K) return;
  const int N = 512;
  int tx = threadIdx.x, ty = threadIdx.y;
#pragma unroll
  for (int i = 0; i < 32; i += 8)
    tile[ty + i][tx] = W[(size_t)(k0 + ty + i) * N + n0 + tx];
  __syncthreads();
#pragma unroll
  for (int i = 0; i < 32; i += 8)
    T[(size_t)(n0 + ty + i) * K + k0 + tx] = f2bf(tile[tx][ty + i]);
}

// ---------------- f32 -> bf16 cast, vectorized ----------------
__global__ void k_cast(const float* __restrict__ in, unsigned short* __restrict__ out, int n8) {
  int i = blockIdx.x * blockDim.x + threadIdx.x;
  int stride = gridDim.x * blockDim.x;
  for (; i < n8; i += stride) {
    f32x4 v0 = *(const f32x4*)(in + (size_t)i * 8);
    f32x4 v1 = *(const f32x4*)(in + (size_t)i * 8 + 4);
    unsigned short tmp[8] __attribute__((aligned(16)));
    tmp[0] = f2bf(v0[0]); tmp[1] = f2bf(v0[1]); tmp[2] = f2bf(v0[2]); tmp[3] = f2bf(v0[3]);
    tmp[4] = f2bf(v1[0]); tmp[5] = f2bf(v1[1]); tmp[6] = f2bf(v1[2]); tmp[7] = f2bf(v1[3]);
    *(i32x4*)(out + (size_t)i * 8) = *(const i32x4*)tmp;
  }
}

// ---------------- GEMM 128x128 (R2-proven): C = A[M][K] * BT[N][K]^T ------------
// ZMODE 0: grid (mx,ny,nz). ZMODE 2: flat grid, z=bid&7, r=bid>>3, m=r>>3, n=r&7.
template<int BIAS_MODE, bool RES, bool OUT_BF16, int ZMODE>
__global__ __launch_bounds__(256, 2) void k_gemm(
    const unsigned short* __restrict__ A, const unsigned short* __restrict__ B,
    const float* __restrict__ bias, const float* __restrict__ resv,
    void* __restrict__ Cv, int M, int N, int K,
    long sA, long sB, long sC, long sR) {
  __shared__ __align__(16) char lds[65536];
  const int t = threadIdx.x, lane = t & 63, wid = t >> 6;
  const int wr = wid >> 1, wc = wid & 1;
  int m0, n0, z;
  if (ZMODE == 2) {
    int bid = blockIdx.x; z = bid & 7; int r = bid >> 3;
    m0 = (r >> 3) * 128; n0 = (r & 7) * 128;
  } else {
    m0 = blockIdx.x * 128; n0 = blockIdx.y * 128; z = blockIdx.z;
  }
  const unsigned short* Ab = A + (size_t)z * sA;
  const unsigned short* Bb = B + (size_t)z * sB;

  const f32x4 fz = {0.f, 0.f, 0.f, 0.f};
  f32x4 acc[4][4];
#pragma unroll
  for (int i = 0; i < 4; i++)
#pragma unroll
    for (int j = 0; j < 4; j++) acc[i][j] = fz;

  const int srow = t >> 3;      // 0..31
  const int schunk = t & 7;

  auto stage = [&](int kk, int buf) {
    const char* a8 = (const char*)Ab;
    const char* b8 = (const char*)Bb;
#pragma unroll
    for (int i = 0; i < 4; i++) {
      int row = i * 32 + srow;
      gld16(a8 + ((size_t)(m0 + row) * K + kk) * 2 + ((schunk ^ (row & 7)) << 4),
            lds + buf * 32768 + i * 4096 + wid * 1024);
    }
#pragma unroll
    for (int i = 0; i < 4; i++) {
      int row = i * 32 + srow;
      gld16(b8 + ((size_t)(n0 + row) * K + kk) * 2 + ((schunk ^ (row & 7)) << 4),
            lds + buf * 32768 + 16384 + i * 4096 + wid * 1024);
    }
  };

  stage(0, 0);
  int buf = 0;
  for (int kk = 0; kk < K; kk += 64) {
    if (kk + 64 < K) {
      stage(kk + 64, buf ^ 1);
      asm volatile("s_waitcnt vmcnt(8)" ::: "memory");
    } else {
      asm volatile("s_waitcnt vmcnt(0)" ::: "memory");
    }
    __builtin_amdgcn_s_barrier();
    const char* As = lds + buf * 32768;
    const char* Bs = As + 16384;
#pragma unroll
    for (int ks = 0; ks < 2; ks++) {
      short8 af[4], bfr[4];
#pragma unroll
      for (int i = 0; i < 4; i++) {
        int r = wr * 64 + i * 16 + (lane & 15);
        af[i] = *(const short8*)(As + r * 128 +
                 (((unsigned)(ks * 64 + (lane >> 4) * 16)) ^ ((unsigned)(r & 7) << 4)));
      }
#pragma unroll
      for (int i = 0; i < 4; i++) {
        int r = wc * 64 + i * 16 + (lane & 15);
        bfr[i] = *(const short8*)(Bs + r * 128 +
                 (((unsigned)(ks * 64 + (lane >> 4) * 16)) ^ ((unsigned)(r & 7) << 4)));
      }
#pragma unroll
      for (int i = 0; i < 4; i++)
#pragma unroll
        for (int j = 0; j < 4; j++)
          acc[i][j] = __builtin_amdgcn_mfma_f32_16x16x32_bf16(af[i], bfr[j], acc[i][j], 0, 0, 0);
    }
    asm volatile("s_waitcnt lgkmcnt(0)" ::: "memory");
    __builtin_amdgcn_s_barrier();
    buf ^= 1;
  }

  const float* res = RES ? (resv + (size_t)z * sR) : nullptr;
  char* Cb = (char*)Cv + (size_t)z * sC * (OUT_BF16 ? 2 : 4);
#pragma unroll
  for (int i = 0; i < 4; i++) {
#pragma unroll
    for (int jj = 0; jj < 4; jj++) {
      int row = m0 + wr * 64 + i * 16 + (lane >> 4) * 4 + jj;
#pragma unroll
      for (int j = 0; j < 4; j++) {
        int col = n0 + wc * 64 + j * 16 + (lane & 15);
        float v = acc[i][j][jj];
        if (BIAS_MODE == 1) v += bias[col];
        if (BIAS_MODE == 2) v += bias[row];
        if (RES) v += res[(size_t)row * N + col];
        if (OUT_BF16) ((unsigned short*)Cb)[(size_t)row * N + col] = f2bf(v);
        else          ((float*)Cb)[(size_t)row * N + col] = v;
      }
    }
  }
}

// ---------------- GEMM 256x256, BK=32, 8 waves (2x4), 3-buffer ring -------------
// R14 configuration: single-phase K-loop, ONE barrier per tile, compiler-
// scheduled lgkmcnt; scalar epilogues (NON-TEMPORAL global stores: outputs are
// either never re-read or capacity-evicted before reuse; NT stops write-
// allocate from evicting live A/B panels). EPI==2 precomputes 1/rowsum in LDS.
// AF32 path (q-GEMM): A read as f32, converted in registers during staging.
// ZMODE 0: grid (mx,ny,nz). ZMODE 1: flat, z=bid&7, r=bid>>3, m=r>>1, n=r&1.
// ZMODE 3: flat, z=bid&7, r=bid>>3, m=r>>2, n=r&3.
// ZMODE 4: flat 256 blocks, xcd=bid&7, idx=bid>>3, n0=(idx&1)*256,
//          m0=((idx>>1)+xcd*16)*256, z=0  (co-locates the n-pair of each
//          m-tile on one XCD so the f32 A-panel is fetched once per XCD L2).
// EPI 0: bias/res. EPI 1: bf16(exp(acc*scale)) + deterministic partial row-sums.
// EPI 2: multiply by invb[row] before bias/res/store (softmax-normalized GEMM).
template<int BIAS_MODE, bool RES, bool OUT_BF16, int ZMODE, int EPI, bool AF32>
__global__ __launch_bounds__(512, 1) void k_gemm3(
    const unsigned short* __restrict__ A, const unsigned short* __restrict__ B,
    const float* __restrict__ bias, const float* __restrict__ resv,
    void* __restrict__ Cv, int M, int N, int K,
    long sA, long sB, long sC, long sR,
    const float* __restrict__ ps, float* __restrict__ psout) {
  __shared__ __align__(16) char lds[99328];   // 3 x 32768 ring + 1024 invb
  const int t = threadIdx.x, lane = t & 63, wid = t >> 6;
  const int wr = wid >> 2, wc = wid & 3;
  const int l15 = lane & 15, g = lane >> 4;
  int m0, n0, z;
  if (ZMODE == 1) {
    int bid = blockIdx.x; z = bid & 7; int r = bid >> 3;
    m0 = (r >> 1) * 256; n0 = (r & 1) * 256;
  } else if (ZMODE == 3) {
    int bid = blockIdx.x; z = bid & 7; int r = bid >> 3;
    m0 = (r >> 2) * 256; n0 = (r & 3) * 256;
  } else if (ZMODE == 4) {
    int bid = blockIdx.x; int xcd = bid & 7; int idx = bid >> 3;
    n0 = (idx & 1) * 256;
    m0 = ((idx >> 1) + xcd * 16) * 256;
    z = 0;
  } else {
    m0 = blockIdx.x * 256; n0 = blockIdx.y * 256; z = blockIdx.z;
  }
  const unsigned short* Ab = A + (size_t)z * sA;
  const float* Af = (const float*)A + (size_t)z * sA;
  const unsigned short* Bb = B + (size_t)z * sB;

  float* invb = (float*)(lds + 98304);   // [256] (EPI==2 only)
  if (EPI == 2) {
    if (t < 256) {
      size_t rr = (size_t)z * 4096 + (m0 + t);
      invb[t] = 1.0f / (ps[rr] + ps[32768 + rr] + ps[65536 + rr] + ps[98304 + rr]);
    }
    __syncthreads();
  }

  const f32x4 fz = {0.f, 0.f, 0.f, 0.f};
  f32x4 acc[8][4];
#pragma unroll
  for (int i = 0; i < 8; i++)
#pragma unroll
    for (int j = 0; j < 4; j++) acc[i][j] = fz;

  // per-lane inverse map for staging: LDS byte p -> logical (row, colbyte)
  int rS[2], cS[2];
#pragma unroll
  for (int u = 0; u < 2; u++) {
    int p = u * 8192 + wid * 1024 + lane * 16;
    int L = p >> 7;
    int q = (p & 127) ^ ((L & 7) << 4);
    rS[u] = 2 * L + (q >> 6);
    cS[u] = q & 63;
  }

  auto stageA = [&](int kk, int buf, int u) {
    gld16((const char*)Ab + ((size_t)(m0 + rS[u]) * K + kk) * 2 + cS[u],
          lds + buf * 32768 + u * 8192 + wid * 1024);
  };
  auto stageB = [&](int kk, int buf, int u) {
    gld16((const char*)Bb + ((size_t)(n0 + rS[u]) * K + kk) * 2 + cS[u],
          lds + buf * 32768 + 16384 + u * 8192 + wid * 1024);
  };

  // AF32 reg-staging: raw f32 A data for one tile (2 sub-steps x 8 floats)
  f32x4 araw[2][2];
  auto loadAraw = [&](int kk) {
#pragma unroll
    for (int u = 0; u < 2; u++) {
      const float* src = Af + (size_t)(m0 + rS[u]) * K + kk + (cS[u] >> 1);
      araw[u][0] = *(const f32x4*)(src);
      araw[u][1] = *(const f32x4*)(src + 4);
    }
  };
  auto writeA = [&](int buf) {
#pragma unroll
    for (int u = 0; u < 2; u++) {
      unsigned short tmp[8] __attribute__((aligned(16)));
#pragma unroll
      for (int e = 0; e < 4; e++) tmp[e] = f2bf(araw[u][0][e]);
#pragma unroll
      for (int e = 0; e < 4; e++) tmp[4 + e] = f2bf(araw[u][1][e]);
      *(i32x4*)(lds + buf * 32768 + u * 8192 + wid * 1024 + lane * 16) = *(const i32x4*)tmp;
    }
  };

  auto ldso = [&](int r, int gg) -> unsigned {
    unsigned L = (unsigned)(r >> 1);
    return L * 128 + ((((unsigned)(r & 1)) * 64 + (unsigned)gg * 16) ^ ((L & 7) << 4));
  };

  const int NT = K >> 5;
  if (AF32) {
    loadAraw(0);
#pragma unroll
    for (int u = 0; u < 2; u++) stageB(0, 0, u);
    writeA(0);
    loadAraw(32);
#pragma unroll
    for (int u = 0; u < 2; u++) stageB(32, 1, u);
    writeA(1);
  } else {
#pragma unroll
    for (int u = 0; u < 2; u++) { stageA(0, 0, u); }
#pragma unroll
    for (int u = 0; u < 2; u++) { stageB(0, 0, u); }
#pragma unroll
    for (int u = 0; u < 2; u++) { stageA(32, 1, u); }
#pragma unroll
    for (int u = 0; u < 2; u++) { stageB(32, 1, u); }
  }

  for (int tt = 0; tt < NT; tt++) {
    if (AF32) {
      asm volatile("s_waitcnt vmcnt(0)" ::: "memory");
    } else if (tt + 1 < NT) {
      asm volatile("s_waitcnt vmcnt(4)" ::: "memory");
    } else {
      asm volatile("s_waitcnt vmcnt(0)" ::: "memory");
    }
    __builtin_amdgcn_s_barrier();
    asm volatile("" ::: "memory");   // fence: no reads hoist above barrier
    const char* As = lds + (tt % 3) * 32768;
    const char* Bs = As + 16384;
    const int kk2 = (tt + 2) << 5;
    const bool st = kk2 < K;
    const int bn = (tt + 2) % 3;

    if (AF32 && st) loadAraw(kk2);   // issue early; consumed after MFMAs

    short8 bfr[4], af[8];
#pragma unroll
    for (int fj = 0; fj < 4; fj++) {
      int r = wc * 64 + fj * 16 + l15;
      bfr[fj] = *(const short8*)(Bs + ldso(r, g));
    }
#pragma unroll
    for (int fi = 0; fi < 8; fi++) {
      int r = wr * 128 + fi * 16 + l15;
      af[fi] = *(const short8*)(As + ldso(r, g));
    }
    if (!AF32 && st) { stageA(kk2, bn, 0); stageA(kk2, bn, 1); stageB(kk2, bn, 0); stageB(kk2, bn, 1); }
    __builtin_amdgcn_s_setprio(1);
#pragma unroll
    for (int fi = 0; fi < 8; fi++)
#pragma unroll
      for (int fj = 0; fj < 4; fj++)
        acc[fi][fj] =
            __builtin_amdgcn_mfma_f32_16x16x32_bf16(af[fi], bfr[fj], acc[fi][fj], 0, 0, 0);
    __builtin_amdgcn_s_setprio(0);
    if (AF32 && st) { writeA(bn); stageB(kk2, bn, 0); stageB(kk2, bn, 1); }
    asm volatile("" ::: "memory");   // fence: no reads sink below this point
  }
  asm volatile("s_waitcnt lgkmcnt(0)" ::: "memory");
  __builtin_amdgcn_s_barrier();   // ring dead; epilogue may reuse LDS (EPI=1 redb)
  asm volatile("" ::: "memory");

  char* Cb = (char*)Cv + (size_t)z * sC * (OUT_BF16 ? 2 : 4);

  if (EPI == 1) {
    // exp epilogue: NT-store bf16(exp(acc*scale)); deterministic partial row-sums.
    const float scale = 0.044194173824159216f;  // 512^-0.5
    float* redb = (float*)lds;                  // [4][256] (ring is dead)
#pragma unroll
    for (int i = 0; i < 8; i++) {
#pragma unroll
      for (int jj = 0; jj < 4; jj++) {
        int rl = wr * 128 + i * 16 + g * 4 + jj;   // row within tile
        int row = m0 + rl;
        float e4 = 0.f;
#pragma unroll
        for (int j = 0; j < 4; j++) {
          int col = n0 + wc * 64 + j * 16 + l15;
          float e = __expf(acc[i][j][jj] * scale);
          unsigned short h = f2bf(e);
          __builtin_nontemporal_store(h, (unsigned short*)Cb + (size_t)row * N + col);
          e4 += bf2f(h);
        }
#pragma unroll
        for (int d = 1; d < 16; d <<= 1) e4 += __shfl_xor(e4, d, 64);
        if (l15 == 0) redb[wc * 256 + rl] = e4;
      }
    }
    __syncthreads();
    if (t < 256) {
      float s4 = redb[t] + redb[256 + t] + redb[512 + t] + redb[768 + t];
      psout[(size_t)(n0 >> 8) * 32768 + (size_t)z * 4096 + (m0 + t)] = s4;
    }
    return;
  }

  const float* res = RES ? (resv + (size_t)z * sR) : nullptr;
#pragma unroll
  for (int i = 0; i < 8; i++) {
#pragma unroll
    for (int jj = 0; jj < 4; jj++) {
      int rl = wr * 128 + i * 16 + g * 4 + jj;
      int row = m0 + rl;
      float inv = 1.0f;
      if (EPI == 2) inv = invb[rl];
#pragma unroll
      for (int j = 0; j < 4; j++) {
        int col = n0 + wc * 64 + j * 16 + l15;
        float v = acc[i][j][jj];
        if (EPI == 2) v *= inv;
        if (BIAS_MODE == 1) v += bias[col];
        if (BIAS_MODE == 2) v += bias[row];
        if (RES) v += res[(size_t)row * N + col];
        if (OUT_BF16)
          __builtin_nontemporal_store(f2bf(v), (unsigned short*)Cb + (size_t)row * N + col);
        else
          __builtin_nontemporal_store(v, (float*)Cb + (size_t)row * N + col);
      }
    }
  }
}

// ---------------- launch ----------------
extern "C" void kernel_launch(void* const* d_in, const int* in_sizes, int n_in,
                              void* d_out, int out_size, void* d_ws, size_t ws_size,
                              hipStream_t stream) {
  (void)in_sizes; (void)n_in; (void)out_size; (void)ws_size;
  const float* x   = (const float*)d_in[0];
  const float* ctx = (const float*)d_in[1];
  const float* Wq  = (const float*)d_in[2];
  const float* bq  = (const float*)d_in[3];
  const float* Wk  = (const float*)d_in[4];
  const float* bk  = (const float*)d_in[5];
  const float* Wv  = (const float*)d_in[6];
  const float* bv  = (const float*)d_in[7];
  const float* Wo  = (const float*)d_in[8];
  const float* bo  = (const float*)d_in[9];
  float* out = (float*)d_out;

  char* ws = (char*)d_ws;
  unsigned short* qb   = (unsigned short*)(ws);              // 33,554,432
  unsigned short* kbuf = (unsigned short*)(ws + 33554432);   //  8,388,608
  unsigned short* Vb   = (unsigned short*)(ws + 41943040);   //  8,388,608 (V row-major)
  unsigned short* UT   = (unsigned short*)(ws + 50331648);   //  8,388,608 (U^T = (V Wo)^T)
  unsigned short* WqT  = (unsigned short*)(ws + 58720256);   //    524,288
  unsigned short* WkT  = (unsigned short*)(ws + 59244544);   //    786,432
  unsigned short* WvT  = (unsigned short*)(ws + 60030976);   //    786,432
  unsigned short* WoT  = (unsigned short*)(ws + 60817408);   //    524,288 -> 61,341,696
  unsigned short* cb   = (unsigned short*)(ws + 61341696);   // 12,582,912 -> 73,924,608
  unsigned short* Sbuf = (unsigned short*)(ws + 73924608);   // 67,108,864 -> 141,033,472
  float* psums = (float*)(ws + 141033472);                   // 524,288

  // all 4 weight transposes in one launch
  k_transpose4<<<dim3(24, 16, 4), dim3(32, 8), 0, stream>>>(
      Wq, Wk, Wv, Wo, WqT, WkT, WvT, WoT);

  k_cast<<<dim3(2048), 256, 0, stream>>>(ctx, cb, 786432);

  // q = x @ Wq + bq -> bf16 [32768][512]   (x cast fused; XCD-coloc n-pairs)
  k_gemm3<1, false, true, 4, 0, true><<<dim3(256), 512, 0, stream>>>(
      (const unsigned short*)x, WqT, bq, nullptr, qb, 32768, 512, 512,
      0, 0, 0, 0, nullptr, nullptr);
  // k = ctx @ Wk + bk -> bf16 [8192][512]
  k_gemm<1, false, true, 0><<<dim3(64, 4, 1), 256, 0, stream>>>(
      cb, WkT, bk, nullptr, kbuf, 8192, 512, 768, 0, 0, 0, 0);
  // V = ctx @ Wv + bv -> bf16 [8192][512] row-major
  k_gemm<1, false, true, 0><<<dim3(64, 4, 1), 256, 0, stream>>>(
      cb, WvT, bv, nullptr, Vb, 8192, 512, 768, 0, 0, 0, 0);
  // UT[b] = (V[b] @ Wo)^T = WoT @ V[b]^T -> bf16 [8][512][1024]  (z->XCD affinity)
  k_gemm<0, false, true, 2><<<dim3(256), 256, 0, stream>>>(
      WoT, Vb, nullptr, nullptr, UT, 512, 1024, 512,
      0, (long)1024 * 512, (long)512 * 1024, 0);
  // Pexp[b] = exp(q[b] k[b]^T * scale) -> bf16, + partial row-sums (softmax fused)
  k_gemm3<0, false, true, 3, 1, false><<<dim3(512), 512, 0, stream>>>(
      qb, kbuf, nullptr, nullptr, Sbuf, 4096, 1024, 512,
      (long)4096 * 512, (long)1024 * 512, (long)4096 * 1024, 0, nullptr, psums);
  // out[b] = (Pexp[b] @ UT[b]^T) / rowsum + bo + x[b] -> f32 (PV and out-proj merged)
  k_gemm3<1, true, false, 1, 2, false><<<dim3(256), 512, 0, stream>>>(
      Sbuf, UT, bo, x, out, 4096, 512, 1024,
      (long)4096 * 1024, (long)512 * 1024, (long)4096 * 512, (long)4096 * 512,
      psums, nullptr);
}